// Round 8
// baseline (123.235 us; speedup 1.0000x reference)
//
#include <hip/hip_runtime.h>

// Problem constants
#define BB   2
#define CIN  256
#define OC3  768
#define NG   4
#define GOC  64
#define C2   32
#define KK   49
#define PP   2304
#define HALF_P 1152

// Guarded Y2 layout: rows -3..50 (54), cols -3..52 at stride 56, 768 ch.
#define RS      56
#define BROWS   54
#define BSTRIDE (BROWS * RS * OC3)          // floats per batch = 2,322,432
#define IOFF    ((3 * RS + 3) * OC3)

// Workspace layout (bytes)
#define Y2_BYTES  (BB * BROWS * RS * OC3 * 4)
#define XT_OFF    Y2_BYTES
#define WT_OFF    (XT_OFF + BB * PP * 512 * 2)

typedef __attribute__((ext_vector_type(8))) short bf16x8;
typedef __attribute__((ext_vector_type(4))) float f32x4;

struct TagH { static constexpr bool value = true;  };
struct TagW { static constexpr bool value = false; };

static __device__ __forceinline__ unsigned short f2bf_rne(float x) {
    unsigned int u = __float_as_uint(x);
    unsigned int r = u + 0x7FFFu + ((u >> 16) & 1u);
    return (unsigned short)(r >> 16);
}
static __device__ __forceinline__ float bf2f(unsigned short h) {
    return __uint_as_float(((unsigned int)h) << 16);
}

// ---------------------------------------------------------------------------
// Fused prep kernel: zero_guard (blocks 0..1079) | convert_w (1080..1847) |
// convert_x (1848..2135).
// ---------------------------------------------------------------------------
#define ROW4  (RS * OC3 / 4)       // 10752 float4 per spatial row
#define REG1  (6 * ROW4)
#define COLS4 (OC3 / 4)
__global__ __launch_bounds__(256) void prep(
    const float* __restrict__ X, const float* __restrict__ W,
    float* __restrict__ Y2, short* __restrict__ Xt, short* __restrict__ Wt)
{
    const int bxx = blockIdx.x;
    const int tid = threadIdx.x;
    if (bxx < 1080) {
        // ---- zero_guard ----
        const int b   = bxx / 540;
        const int idx = (bxx - b * 540) * 256 + tid;   // 0..138239
        float4* Yb = (float4*)(Y2 + (size_t)b * BSTRIDE);
        const float4 z = make_float4(0.f, 0.f, 0.f, 0.f);
        if (idx < REG1) {
            int r6  = idx / ROW4;
            int rem = idx - r6 * ROW4;
            int r   = (r6 < 3) ? r6 : 48 + r6;
            Yb[r * ROW4 + rem] = z;
        } else {
            int i2  = idx - REG1;
            int r   = 3 + i2 / (8 * COLS4);
            int rem = i2 - (r - 3) * (8 * COLS4);
            int cg  = rem / COLS4;
            int c   = (cg < 3) ? cg : 48 + cg;
            int ch4 = rem - cg * COLS4;
            Yb[(r * RS + c) * COLS4 + ch4] = z;
        }
    } else if (bxx < 1848) {
        // ---- convert_w ----
        int t = (bxx - 1080) * 256 + tid;              // 0..196607
        int o = t >> 8, c = t & 255;
        float v = W[t];
        unsigned short hi = f2bf_rne(v);
        unsigned short lo = f2bf_rne(v - bf2f(hi));
        Wt[(size_t)o * 512 + c]       = (short)hi;
        Wt[(size_t)o * 512 + 256 + c] = (short)lo;
    } else {
        // ---- convert_x ----
        __shared__ float tile[64][65];
        const int cx = bxx - 1848;                     // 0..287
        const int p0 = (cx % 36) * 64;
        const int c0 = ((cx / 36) & 3) * 64;
        const int b  = cx / 144;
        const float* Xb = X + (size_t)b * CIN * PP;
        #pragma unroll
        for (int r = 0; r < 16; ++r) {
            int idx = r * 256 + tid;
            int c = idx >> 6, p = idx & 63;
            tile[c][p] = Xb[(size_t)(c0 + c) * PP + p0 + p];
        }
        __syncthreads();
        short* Xo = Xt + (size_t)b * PP * 512;
        #pragma unroll
        for (int r = 0; r < 16; ++r) {
            int idx = r * 256 + tid;
            int p = idx >> 6, c = idx & 63;
            float v = tile[c][p];
            unsigned short hi = f2bf_rne(v);
            unsigned short lo = f2bf_rne(v - bf2f(hi));
            size_t base = (size_t)(p0 + p) * 512 + c0 + c;
            Xo[base]       = (short)hi;
            Xo[base + 256] = (short)lo;
        }
    }
}

// ---------------------------------------------------------------------------
// Kernel 1: conv as split-bf16 MFMA GEMM, 3-term product (r7, unchanged).
// ---------------------------------------------------------------------------
#define LDA 40   // shorts per LDS row (32 + 8 pad)

__global__ __launch_bounds__(256, 4) void conv_mfma(
    const short* __restrict__ Wt,   // (768, 512)
    const short* __restrict__ Xt,   // (B, 2304, 512)
    float* __restrict__ Y2)
{
    __shared__ short As[64 * LDA];
    __shared__ short Bs[64 * LDA];

    const int tid = threadIdx.x;
    const int bn  = blockIdx.x;       // p tile (36)
    const int bm  = blockIdx.y;       // o tile (12)
    const int b   = blockIdx.z;
    const int om0 = bm * 64, pn0 = bn * 64;

    const int lane = tid & 63, w = tid >> 6;
    const int oq = (w & 1) * 32, pq = (w >> 1) * 32;
    const int ln15 = lane & 15, q = lane >> 4;

    const int  lrow  = (tid & 127) >> 1;
    const int  lsoff = (tid & 1) * 16;
    const bool isA   = tid < 128;
    const short* gA = Wt + (size_t)(om0 + lrow) * 512 + lsoff;
    const short* gB = Xt + (size_t)b * PP * 512 + (size_t)(pn0 + lrow) * 512 + lsoff;
    const short* gsrc = isA ? gA : gB;
    short* ldst = (isA ? As : Bs) + lrow * LDA + lsoff;

    f32x4 acc[2][2] = {};

    for (int k0 = 0; k0 < 768; k0 += 32) {
        const int wk = (k0 < 256) ? k0 : k0 - 256;   // W: hi, hi, lo
        const int xk = (k0 < 512) ? k0 : k0 - 512;   // X: hi, lo, hi
        const int kk = isA ? wk : xk;
        uint4 v0 = *(const uint4*)(gsrc + kk);
        uint4 v1 = *(const uint4*)(gsrc + kk + 8);
        __syncthreads();
        *(uint4*)ldst       = v0;
        *(uint4*)(ldst + 8) = v1;
        __syncthreads();

        bf16x8 af[2], bf[2];
        #pragma unroll
        for (int i = 0; i < 2; ++i) {
            af[i] = *(const bf16x8*)&As[(oq + i * 16 + ln15) * LDA + q * 8];
            bf[i] = *(const bf16x8*)&Bs[(pq + i * 16 + ln15) * LDA + q * 8];
        }
        #pragma unroll
        for (int i = 0; i < 2; ++i)
            #pragma unroll
            for (int j = 0; j < 2; ++j)
                acc[i][j] = __builtin_amdgcn_mfma_f32_16x16x32_bf16(
                    af[i], bf[j], acc[i][j], 0, 0, 0);
    }

    float* Yb = Y2 + (size_t)b * BSTRIDE + IOFF;
    #pragma unroll
    for (int i = 0; i < 2; ++i) {
        #pragma unroll
        for (int j = 0; j < 2; ++j) {
            int o = om0 + oq + i * 16 + q * 4;
            int p = pn0 + pq + j * 16 + ln15;
            int h = p / 48, ww = p - h * 48;
            *(f32x4*)&Yb[(size_t)(h * RS + ww) * OC3 + o] = acc[i][j];
        }
    }
}

// ---------------------------------------------------------------------------
// Kernel 2: LDS-tiled attention (see theory). Block = 4 consecutive p'.
// Alignment proof: the 4 q' span p0 = 8m..8m+7; 8m mod 48 <= 40 so all in
// one p0-row -> shared ph0; 4|48 -> shared ph; 4|1152 -> shared t,g,b.
// Stage K 7x14x32 + V 7x10x64 + Q 4x64 (31.5 KB LDS) via 1968 float4;
// compute phase is pure LDS/VALU with immediate ds_read offsets.
// ---------------------------------------------------------------------------
__global__ __launch_bounds__(256, 4) void attn_kernel(
    const float* __restrict__ Y2,
    const float* __restrict__ rpe_h,  // (4,1,7,1,32)
    const float* __restrict__ rpe_w,  // (4,1,1,7,32)
    float* __restrict__ out)          // (B, 256, 48, 48)
{
    __shared__ float Ks[7 * 14 * 32];   // [row][col][c]
    __shared__ float Vs[7 * 10 * 64];   // [row][col][ch]
    __shared__ float Qs[4 * 64];        // [p'][ch]
    __shared__ float xpose[4][65];

    const int tid  = threadIdx.x;
    const int lane = tid & 63;
    const int w    = tid >> 6;
    const int bx     = blockIdx.x;
    const int wblock = (bx & 7) * 576 + (bx >> 3);
    const int wid0   = wblock * 4;
    const int pq0  = wid0 % PP;
    const int g    = (wid0 / PP) & (NG - 1);
    const int b    = wid0 / (PP * NG);
    const int ph   = pq0 / 48;
    const int pws  = pq0 - ph * 48;        // pw of wave 0; this wave: pws + w
    const int t    = (pq0 >= HALF_P) ? 1 : 0;
    const int qp0  = pq0 - t * HALF_P;
    const int p00  = 2 * qp0;
    const int ph0  = p00 / 48;
    const int w0   = p00 - ph0 * 48;       // pw0 of wave 0; this wave: w0 + 2w
    const int g2   = 2 * g + t;
    const bool use_h = (g2 < NG);
    const int  kch   = use_h ? (CIN + g2 * GOC) : (CIN + (g2 - NG) * GOC + C2);
    const int  vch   = 2 * CIN + g * GOC;

    const float* Yb = Y2 + (size_t)b * BSTRIDE + IOFF;

    // ---- staging: 1968 float4 across 256 threads ----
    #pragma unroll
    for (int it = 0; it < 8; ++it) {
        int idx = it * 256 + tid;
        if (idx < 784) {                      // K slab: 98 runs x 8 f4
            int run = idx >> 3, f4o = idx & 7;
            int row = run / 14, col = run - row * 14;
            const float* src = Yb + (long)((ph0 + row - 3) * RS + (w0 + col - 3)) * OC3
                               + kch + f4o * 4;
            *(float4*)&Ks[run * 32 + f4o * 4] = *(const float4*)src;
        } else if (idx < 1904) {              // V slab: 70 runs x 16 f4
            int r = idx - 784;
            int run = r >> 4, f4o = r & 15;
            int row = run / 10, col = run - row * 10;
            const float* src = Yb + (long)((ph + row - 3) * RS + (pws + col - 3)) * OC3
                               + vch + f4o * 4;
            *(float4*)&Vs[run * 64 + f4o * 4] = *(const float4*)src;
        } else if (idx < 1968) {              // Q: 4 x 16 f4
            int r = idx - 1904;
            int pi = r >> 4, f4o = r & 15;
            const float* src = Yb + (long)(ph * RS + pws + pi) * OC3 + g * GOC + f4o * 4;
            *(float4*)&Qs[pi * 64 + f4o * 4] = *(const float4*)src;
        }
    }

    // rpe in named registers (tiny, L2-hot)
    const int  c  = lane & 31;
    const bool hi = (lane >= 32);
    const float* rb = use_h ? (rpe_h + g2 * 7 * C2) : (rpe_w + (g2 - NG) * 7 * C2);
    const float R0 = rb[0 * C2 + c], R1 = rb[1 * C2 + c], R2 = rb[2 * C2 + c],
                R3 = rb[3 * C2 + c], R4 = rb[4 * C2 + c], R5 = rb[5 * C2 + c],
                R6 = rb[6 * C2 + c];

    __syncthreads();

    const float qv = Qs[w * GOC + lane];
    const float* kls = Ks + w * 64 + c;      // + imm (i*14+j+h1)*32
    const float* vls = Vs + w * 64 + lane;   // + imm (i*10+j)*64

    auto rget = [&](int idx) -> float {
        return idx == 0 ? R0 : idx == 1 ? R1 : idx == 2 ? R2 :
               idx == 3 ? R3 : idx == 4 ? R4 : idx == 5 ? R5 : R6;
    };

    auto tree = [&](auto tag) -> float {
        constexpr bool UH = decltype(tag)::value;
        auto chunkprod = [&](int l) -> float {
            int m0 = 2 * l,     h10 = (m0 >= KK), k0 = m0 - KK * h10;
            int m1 = 2 * l + 1, h11 = (m1 >= KK), k1 = m1 - KK * h11;
            int i0 = k0 / 7, j0 = k0 % 7, i1 = k1 / 7, j1 = k1 % 7;
            int d0 = (i0 * 14 + j0 + h10) * 32;    // compile-time
            int d1 = (i1 * 14 + j1 + h11) * 32;    // compile-time
            float kv = kls[hi ? d1 : d0];
            float ra = UH ? rget(i0) : rget(j0);
            float rc = UH ? rget(i1) : rget(j1);
            kv += hi ? rc : ra;
            return qv * kv;
        };
        float sv[32];
        #pragma unroll
        for (int jj = 0; jj < 32; ++jj) {
            if (2 * jj >= KK) { sv[jj] = 0.f; continue; }
            float pa = chunkprod(2 * jj);
            float pb = (2 * jj + 1 < KK) ? chunkprod(2 * jj + 1) : 0.f;
            float u  = (lane & 1) ? pb : pa;
            float ww = (lane & 1) ? pa : pb;
            sv[jj] = u + __shfl_xor(ww, 1, 64);
        }
        #pragma unroll
        for (int d = 2; d < 64; d <<= 1) {
            #pragma unroll
            for (int i = 0; i < 32; i += d) {
                float a  = sv[i], bb = sv[i + d / 2];
                float u  = (lane & d) ? bb : a;
                float ww = (lane & d) ? a : bb;
                sv[i] = u + __shfl_xor(ww, d, 64);
            }
        }
        return sv[0];
    };

    const float logit = use_h ? tree(TagH{}) : tree(TagW{});

    float mx = logit;
    #pragma unroll
    for (int d = 1; d < 64; d <<= 1)
        mx = fmaxf(mx, __shfl_xor(mx, d, 64));
    float e = (lane < KK) ? __expf(logit - mx) : 0.f;
    float ssum = e;
    #pragma unroll
    for (int d = 1; d < 64; d <<= 1)
        ssum += __shfl_xor(ssum, d, 64);
    const float att = e / ssum;

    // ---- value: lane = channel, taps from LDS with immediate offsets ----
    float acc = 0.f;
    #pragma unroll
    for (int k = 0; k < KK; ++k) {
        int i = k / 7, j = k % 7;
        float ak = __uint_as_float(
            __builtin_amdgcn_readlane(__float_as_uint(att), k));
        acc = fmaf(ak, vls[(i * 10 + j) * 64], acc);
    }

    xpose[w][lane] = acc;
    __syncthreads();
    const int ch = tid >> 2;
    const int w2 = tid & 3;
    out[((size_t)b * 256 + g * GOC + ch) * PP + pq0 + w2] = xpose[w2][ch];
}

// ---------------------------------------------------------------------------
extern "C" void kernel_launch(void* const* d_in, const int* in_sizes, int n_in,
                              void* d_out, int out_size, void* d_ws, size_t ws_size,
                              hipStream_t stream)
{
    const float* x  = (const float*)d_in[0];
    const float* w  = (const float*)d_in[1];
    const float* rh = (const float*)d_in[2];
    const float* rw = (const float*)d_in[3];

    float* Y2 = (float*)d_ws;
    short* Xt = (short*)((char*)d_ws + XT_OFF);
    short* Wt = (short*)((char*)d_ws + WT_OFF);

    prep<<<2136, 256, 0, stream>>>(x, w, Y2, Xt, Wt);
    conv_mfma<<<dim3(36, 12, BB), 256, 0, stream>>>(Wt, Xt, Y2);
    attn_kernel<<<(BB * NG * PP) / 4, 256, 0, stream>>>(Y2, rh, rw, (float*)d_out);
}

// Round 9
// 119.675 us; speedup vs baseline: 1.0298x; 1.0298x over previous
//
#include <hip/hip_runtime.h>

// Problem constants
#define BB   2
#define CIN  256
#define OC3  768
#define NG   4
#define GOC  64
#define C2   32
#define KK   49
#define PP   2304
#define HALF_P 1152

// Guarded Y2 layout: rows -3..50 (54), cols -3..52 at stride 56, 768 ch.
#define RS      56
#define BROWS   54
#define BSTRIDE (BROWS * RS * OC3)          // floats per batch = 2,322,432
#define IOFF    ((3 * RS + 3) * OC3)

// Workspace layout (bytes)
#define Y2_BYTES  (BB * BROWS * RS * OC3 * 4)
#define XT_OFF    Y2_BYTES
#define WT_OFF    (XT_OFF + BB * PP * 512 * 2)

typedef __attribute__((ext_vector_type(8))) short bf16x8;
typedef __attribute__((ext_vector_type(4))) float f32x4;

struct TagH { static constexpr bool value = true;  };
struct TagW { static constexpr bool value = false; };

static __device__ __forceinline__ unsigned short f2bf_rne(float x) {
    unsigned int u = __float_as_uint(x);
    unsigned int r = u + 0x7FFFu + ((u >> 16) & 1u);
    return (unsigned short)(r >> 16);
}
static __device__ __forceinline__ float bf2f(unsigned short h) {
    return __uint_as_float(((unsigned int)h) << 16);
}

// DPP lane-move on the VALU pipe (no DS). CTRL: 0xB1=quad xor1, 0x4E=quad
// xor2, 0x141=row_half_mirror (xor-pairs across quads of 8), 0x128=row_ror:8
// (= xor8 within row16 after 8-group uniformity).
template<int CTRL>
static __device__ __forceinline__ float dpp_mov_f(float x) {
    return __int_as_float(__builtin_amdgcn_update_dpp(
        0, __float_as_int(x), CTRL, 0xF, 0xF, true));
}

// ---------------------------------------------------------------------------
// Fused prep kernel: zero_guard (blocks 0..1079) | convert_w (1080..1847) |
// convert_x (1848..2135). (r8, unchanged)
// ---------------------------------------------------------------------------
#define ROW4  (RS * OC3 / 4)       // 10752 float4 per spatial row
#define REG1  (6 * ROW4)
#define COLS4 (OC3 / 4)
__global__ __launch_bounds__(256) void prep(
    const float* __restrict__ X, const float* __restrict__ W,
    float* __restrict__ Y2, short* __restrict__ Xt, short* __restrict__ Wt)
{
    const int bxx = blockIdx.x;
    const int tid = threadIdx.x;
    if (bxx < 1080) {
        const int b   = bxx / 540;
        const int idx = (bxx - b * 540) * 256 + tid;
        float4* Yb = (float4*)(Y2 + (size_t)b * BSTRIDE);
        const float4 z = make_float4(0.f, 0.f, 0.f, 0.f);
        if (idx < REG1) {
            int r6  = idx / ROW4;
            int rem = idx - r6 * ROW4;
            int r   = (r6 < 3) ? r6 : 48 + r6;
            Yb[r * ROW4 + rem] = z;
        } else {
            int i2  = idx - REG1;
            int r   = 3 + i2 / (8 * COLS4);
            int rem = i2 - (r - 3) * (8 * COLS4);
            int cg  = rem / COLS4;
            int c   = (cg < 3) ? cg : 48 + cg;
            int ch4 = rem - cg * COLS4;
            Yb[(r * RS + c) * COLS4 + ch4] = z;
        }
    } else if (bxx < 1848) {
        int t = (bxx - 1080) * 256 + tid;
        int o = t >> 8, c = t & 255;
        float v = W[t];
        unsigned short hi = f2bf_rne(v);
        unsigned short lo = f2bf_rne(v - bf2f(hi));
        Wt[(size_t)o * 512 + c]       = (short)hi;
        Wt[(size_t)o * 512 + 256 + c] = (short)lo;
    } else {
        __shared__ float tile[64][65];
        const int cx = bxx - 1848;
        const int p0 = (cx % 36) * 64;
        const int c0 = ((cx / 36) & 3) * 64;
        const int b  = cx / 144;
        const float* Xb = X + (size_t)b * CIN * PP;
        #pragma unroll
        for (int r = 0; r < 16; ++r) {
            int idx = r * 256 + tid;
            int c = idx >> 6, p = idx & 63;
            tile[c][p] = Xb[(size_t)(c0 + c) * PP + p0 + p];
        }
        __syncthreads();
        short* Xo = Xt + (size_t)b * PP * 512;
        #pragma unroll
        for (int r = 0; r < 16; ++r) {
            int idx = r * 256 + tid;
            int p = idx >> 6, c = idx & 63;
            float v = tile[c][p];
            unsigned short hi = f2bf_rne(v);
            unsigned short lo = f2bf_rne(v - bf2f(hi));
            size_t base = (size_t)(p0 + p) * 512 + c0 + c;
            Xo[base]       = (short)hi;
            Xo[base + 256] = (short)lo;
        }
    }
}

// ---------------------------------------------------------------------------
// Kernel 1: conv as split-bf16 MFMA GEMM, 3-term product (r7, unchanged).
// ---------------------------------------------------------------------------
#define LDA 40   // shorts per LDS row (32 + 8 pad)

__global__ __launch_bounds__(256, 4) void conv_mfma(
    const short* __restrict__ Wt,   // (768, 512)
    const short* __restrict__ Xt,   // (B, 2304, 512)
    float* __restrict__ Y2)
{
    __shared__ short As[64 * LDA];
    __shared__ short Bs[64 * LDA];

    const int tid = threadIdx.x;
    const int bn  = blockIdx.x;       // p tile (36)
    const int bm  = blockIdx.y;       // o tile (12)
    const int b   = blockIdx.z;
    const int om0 = bm * 64, pn0 = bn * 64;

    const int lane = tid & 63, w = tid >> 6;
    const int oq = (w & 1) * 32, pq = (w >> 1) * 32;
    const int ln15 = lane & 15, q = lane >> 4;

    const int  lrow  = (tid & 127) >> 1;
    const int  lsoff = (tid & 1) * 16;
    const bool isA   = tid < 128;
    const short* gA = Wt + (size_t)(om0 + lrow) * 512 + lsoff;
    const short* gB = Xt + (size_t)b * PP * 512 + (size_t)(pn0 + lrow) * 512 + lsoff;
    const short* gsrc = isA ? gA : gB;
    short* ldst = (isA ? As : Bs) + lrow * LDA + lsoff;

    f32x4 acc[2][2] = {};

    for (int k0 = 0; k0 < 768; k0 += 32) {
        const int wk = (k0 < 256) ? k0 : k0 - 256;   // W: hi, hi, lo
        const int xk = (k0 < 512) ? k0 : k0 - 512;   // X: hi, lo, hi
        const int kk = isA ? wk : xk;
        uint4 v0 = *(const uint4*)(gsrc + kk);
        uint4 v1 = *(const uint4*)(gsrc + kk + 8);
        __syncthreads();
        *(uint4*)ldst       = v0;
        *(uint4*)(ldst + 8) = v1;
        __syncthreads();

        bf16x8 af[2], bf[2];
        #pragma unroll
        for (int i = 0; i < 2; ++i) {
            af[i] = *(const bf16x8*)&As[(oq + i * 16 + ln15) * LDA + q * 8];
            bf[i] = *(const bf16x8*)&Bs[(pq + i * 16 + ln15) * LDA + q * 8];
        }
        #pragma unroll
        for (int i = 0; i < 2; ++i)
            #pragma unroll
            for (int j = 0; j < 2; ++j)
                acc[i][j] = __builtin_amdgcn_mfma_f32_16x16x32_bf16(
                    af[i], bf[j], acc[i][j], 0, 0, 0);
    }

    float* Yb = Y2 + (size_t)b * BSTRIDE + IOFF;
    #pragma unroll
    for (int i = 0; i < 2; ++i) {
        #pragma unroll
        for (int j = 0; j < 2; ++j) {
            int o = om0 + oq + i * 16 + q * 4;
            int p = pn0 + pq + j * 16 + ln15;
            int h = p / 48, ww = p - h * 48;
            *(f32x4*)&Yb[(size_t)(h * RS + ww) * OC3 + o] = acc[i][j];
        }
    }
}

// ---------------------------------------------------------------------------
// Kernel 2: attention, DPP-reduced. One wave per (b,g,p'), 4 p'/block.
// Lane layout for logits: tsub = lane>>3 (8 taps/iter), cq = lane&7
// (channel quad). Per iter: 2 ds_read_b128 (K quads for tap halves m0/m1)
// + 8 fma + rpe terms; reduce over the 8 consecutive lanes with 3 VALU-DPP
// adds (no DS). lane x ends holding logit[8*(x&7) + (x>>3)].
// Softmax: 4 DPP stages + 2 shfl_xor. V phase: 49 global b32 (VMEM pipe).
// K slab in LDS: [98 spatial][32 ch] at stride 36 (bank decorrelation).
// ---------------------------------------------------------------------------
#define KSTR 36
__global__ __launch_bounds__(256, 4) void attn_kernel(
    const float* __restrict__ Y2,
    const float* __restrict__ rpe_h,  // (4,1,7,1,32)
    const float* __restrict__ rpe_w,  // (4,1,1,7,32)
    float* __restrict__ out)          // (B, 256, 48, 48)
{
    __shared__ float Ks[98 * KSTR];
    __shared__ float xpose[4][65];

    const int tid  = threadIdx.x;
    const int lane = tid & 63;
    const int w    = tid >> 6;
    const int bx     = blockIdx.x;
    const int wblock = (bx & 7) * 576 + (bx >> 3);
    const int wid0   = wblock * 4;
    const int pq0  = wid0 % PP;
    const int g    = (wid0 / PP) & (NG - 1);
    const int b    = wid0 / (PP * NG);
    const int ph   = pq0 / 48;
    const int pws  = pq0 - ph * 48;        // pw of wave 0; this wave: pws + w
    const int t    = (pq0 >= HALF_P) ? 1 : 0;
    const int qp0  = pq0 - t * HALF_P;
    const int p00  = 2 * qp0;
    const int ph0  = p00 / 48;
    const int w0   = p00 - ph0 * 48;       // pw0 of wave 0; this wave: w0 + 2w
    const int g2   = 2 * g + t;
    const bool use_h = (g2 < NG);
    const int  kch   = use_h ? (CIN + g2 * GOC) : (CIN + (g2 - NG) * GOC + C2);
    const int  vch   = 2 * CIN + g * GOC;

    const float* Yb = Y2 + (size_t)b * BSTRIDE + IOFF;

    // ---- stage K slab: 98 cells x 32 ch, LDS stride 36 ----
    #pragma unroll
    for (int it = 0; it < 4; ++it) {
        int idx = it * 256 + tid;
        if (idx < 784) {
            int run = idx >> 3, f4o = idx & 7;
            int row = run / 14, col = run - row * 14;
            const float* src = Yb + (long)((ph0 + row - 3) * RS + (w0 + col - 3)) * OC3
                               + kch + f4o * 4;
            *(float4*)&Ks[run * KSTR + f4o * 4] = *(const float4*)src;
        }
    }

    const int tsub = lane >> 3;
    const int cq   = lane & 7;

    // ---- Q quads direct from global ----
    const float* qbase = Yb + (long)(ph * RS + pws + w) * OC3 + g * GOC;
    const float4 qlo = *(const float4*)(qbase + 4 * cq);
    const float4 qhi = *(const float4*)(qbase + 32 + 4 * cq);

    // ---- rpe row dots (per-lane 4-ch partials), named regs ----
    const float* rb = use_h ? (rpe_h + g2 * 7 * C2) : (rpe_w + (g2 - NG) * 7 * C2);
    float A0, A1, A2, A3, A4, A5, A6, H0, H1, H2, H3, H4, H5, H6;
    {
        auto rl = [&](int r, float& Ar, float& Hr) {
            float4 v = *(const float4*)(rb + r * 32 + 4 * cq);
            Ar = qlo.x * v.x + qlo.y * v.y + qlo.z * v.z + qlo.w * v.w;
            Hr = qhi.x * v.x + qhi.y * v.y + qhi.z * v.z + qhi.w * v.w;
        };
        rl(0, A0, H0); rl(1, A1, H1); rl(2, A2, H2); rl(3, A3, H3);
        rl(4, A4, H4); rl(5, A5, H5); rl(6, A6, H6);
    }
    auto selA = [&](int i) -> float {
        return i == 0 ? A0 : i == 1 ? A1 : i == 2 ? A2 :
               i == 3 ? A3 : i == 4 ? A4 : i == 5 ? A5 : A6;
    };
    auto selH = [&](int i) -> float {
        return i == 0 ? H0 : i == 1 ? H1 : i == 2 ? H2 :
               i == 3 ? H3 : i == 4 ? H4 : i == 5 ? H5 : H6;
    };

    __syncthreads();

    // ---- logits ----
    auto logits = [&](auto tag) -> float {
        constexpr bool UH = decltype(tag)::value;
        float lg = 0.f;
        #pragma unroll
        for (int l = 0; l < 7; ++l) {
            int kp = 8 * l + tsub;
            int m0 = 2 * kp, m1 = m0 + 1;
            int h10 = (m0 >= KK) ? 1 : 0; int k0 = m0 - KK * h10;
            int h11 = (m1 >= KK) ? 1 : 0; int k1 = m1 - KK * h11;
            int i0 = (k0 * 37) >> 8; int j0 = k0 - 7 * i0;
            int i1 = (k1 * 37) >> 8; int j1 = k1 - 7 * i1;
            int offA = (i0 * 14 + 2 * w + j0 + h10) * KSTR + 4 * cq;
            int offB = (i1 * 14 + 2 * w + j1 + h11) * KSTR + 4 * cq;
            offA = min(offA, 98 * KSTR - 4);        // clamp tap>=49 garbage
            offB = min(offB, 98 * KSTR - 4);
            float4 ka = *(const float4*)&Ks[offA];
            float4 kb = *(const float4*)&Ks[offB];
            float part = qlo.x * ka.x + qlo.y * ka.y + qlo.z * ka.z + qlo.w * ka.w
                       + qhi.x * kb.x + qhi.y * kb.y + qhi.z * kb.z + qhi.w * kb.w
                       + (UH ? selA(i0) : selA(j0))
                       + (UH ? selH(i1) : selH(j1));
            // reduce over the 8 consecutive lanes (cq) on the VALU pipe
            part += dpp_mov_f<0xB1>(part);
            part += dpp_mov_f<0x4E>(part);
            part += dpp_mov_f<0x141>(part);
            if (l == 6) part = (tsub == 0) ? part : 0.f;   // taps 49..55 invalid
            lg = (cq == l) ? part : lg;
        }
        return lg;
    };
    const float logit = use_h ? logits(TagH{}) : logits(TagW{});
    // lane x holds logit[8*(x&7) + (x>>3)]; lanes with x&7 == 7 hold 0 (pad).

    // ---- softmax over the wave ----
    float mx = logit;
    mx = fmaxf(mx, dpp_mov_f<0xB1>(mx));
    mx = fmaxf(mx, dpp_mov_f<0x4E>(mx));
    mx = fmaxf(mx, dpp_mov_f<0x141>(mx));
    mx = fmaxf(mx, dpp_mov_f<0x128>(mx));
    mx = fmaxf(mx, __shfl_xor(mx, 16, 64));
    mx = fmaxf(mx, __shfl_xor(mx, 32, 64));
    const int Lx = 8 * cq + tsub;
    float e = (Lx < KK) ? __expf(logit - mx) : 0.f;
    float ssum = e;
    ssum += dpp_mov_f<0xB1>(ssum);
    ssum += dpp_mov_f<0x4E>(ssum);
    ssum += dpp_mov_f<0x141>(ssum);
    ssum += dpp_mov_f<0x128>(ssum);
    ssum += __shfl_xor(ssum, 16, 64);
    ssum += __shfl_xor(ssum, 32, 64);
    const float att = e / ssum;

    // ---- value accumulation: lane = output channel; V from global (VMEM) ----
    float acc = 0.f;
    const float* vb = Yb + (long)(ph * RS + pws + w) * OC3 + vch + lane;
    #pragma unroll
    for (int k = 0; k < KK; ++k) {
        int i = k / 7, j = k % 7;                       // compile-time
        int doff = ((i - 3) * RS + (j - 3)) * OC3;      // compile-time
        int src  = 8 * (k & 7) + (k >> 3);              // compile-time
        float ak = __uint_as_float(
            __builtin_amdgcn_readlane(__float_as_uint(att), src));
        acc = fmaf(ak, vb[doff], acc);
    }

    // ---- LDS transpose + grouped 16B stores ----
    xpose[w][lane] = acc;
    __syncthreads();
    const int ch = tid >> 2;
    const int w2 = tid & 3;
    out[((size_t)b * 256 + g * GOC + ch) * PP + pq0 + w2] = xpose[w2][ch];
}

// ---------------------------------------------------------------------------
extern "C" void kernel_launch(void* const* d_in, const int* in_sizes, int n_in,
                              void* d_out, int out_size, void* d_ws, size_t ws_size,
                              hipStream_t stream)
{
    const float* x  = (const float*)d_in[0];
    const float* w  = (const float*)d_in[1];
    const float* rh = (const float*)d_in[2];
    const float* rw = (const float*)d_in[3];

    float* Y2 = (float*)d_ws;
    short* Xt = (short*)((char*)d_ws + XT_OFF);
    short* Wt = (short*)((char*)d_ws + WT_OFF);

    prep<<<2136, 256, 0, stream>>>(x, w, Y2, Xt, Wt);
    conv_mfma<<<dim3(36, 12, BB), 256, 0, stream>>>(Wt, Xt, Y2);
    attn_kernel<<<(BB * NG * PP) / 4, 256, 0, stream>>>(Y2, rh, rw, (float*)d_out);
}